// Round 19
// baseline (29.807 us; speedup 1.0000x reference)
//
#include <hip/hip_runtime.h>

// HOG layer: (32,1,512,512) f32 -> (32,10,64,64) f32
// CORRECTNESS-PINNED decisions (R12 pass, absmax 0.0371):
//   f32 seq conv (row-major sequential taps) -> bin = floor(fl32(atan2f*C10))
//   mod 10 with boundary-ambiguity 50/50 split (eps window, mag<4.6 gate)
//   -> 8x8 mean pool.
// Fast path (R17, bit-identical): octant-reduced Hastings deg-9 atan in w10
// units; |w - rint(w)| < 1.25e-4 -> flagged -> VERBATIM R12 slow path.
// R19 (scheduling only): stage-separated ILP. All 8 pixels advance together
// through conv -> trans(sqrt/rcp) -> poly -> flag/bin -> scatter, giving the
// scheduler 8 independent chains (R17/18 were latency-bound on one ~25-op
// chain/pixel). Slow path hoisted after the scatter under ONE if(flags),
// reusing saved gx/gy (no conv recompute; row[] dies early). Deposit order ==
// R16's (validated bit-identical: fast deposits then flagged deposits).

namespace {
constexpr int H = 512, W = 512, NB = 10;
}

__global__ __launch_bounds__(256) void hog_kernel(const float* __restrict__ xin,
                                                  float* __restrict__ out) {
    const int tid  = threadIdx.x;
    const int wid  = (blockIdx.x * blockDim.x + tid) >> 6;
    const int lane = tid & 63;

    const int n    = wid >> 9;        // image
    const int rem  = wid & 511;
    const int ph   = rem >> 3;        // pooled row 0..63
    const int pwg  = rem & 7;         // group of 8 pooled cols
    const int cell = lane >> 3;       // pooled col within group
    const int r    = lane & 7;        // pixel row within cell

    const int pw = pwg * 8 + cell;
    const int y  = ph * 8 + r;
    const int x0 = pw * 8;

    const float* img = xin + (size_t)n * H * W;

    // pinned: C10 = fl32( fl32(1/pi32) * 10 )
    const float PI32 = 3.14159274101257324f;            // 0x40490fdb
    const float C10  = __fmul_rn(__fdiv_rn(1.0f, PI32), 10.0f);

    // Hastings (A&S 4.4.47) atan coeffs scaled by 10/pi (w10 units) -- pinned
    const float P0 =  3.1826723f, P1 = -1.0513758f, P2 = 0.5734066f,
                P3 = -0.2709868f, P4 =  0.0663202f;
    const float EPSW = 1.25e-4f;

    // ---- stage A: strip preload, rows y-1..y+1, cols x0-1..x0+8 ----
    float row[3][10];
#pragma unroll
    for (int dy = 0; dy < 3; ++dy) {
        const int ry = y - 1 + dy;
        if (ry >= 0 && ry < H) {
            const float* p = img + (size_t)ry * W + x0;
            row[dy][0] = (x0 > 0) ? p[-1] : 0.0f;
            const float4 a = *reinterpret_cast<const float4*>(p);      // 32B-aligned
            const float4 b = *reinterpret_cast<const float4*>(p + 4);
            row[dy][1] = a.x; row[dy][2] = a.y; row[dy][3] = a.z; row[dy][4] = a.w;
            row[dy][5] = b.x; row[dy][6] = b.y; row[dy][7] = b.z; row[dy][8] = b.w;
            row[dy][9] = (x0 + 8 < W) ? p[8] : 0.0f;
        } else {
#pragma unroll
            for (int i = 0; i < 10; ++i) row[dy][i] = 0.0f;
        }
    }

    // ---- stage B: conv x8 (pinned order); row[] dead afterwards ----
    float gx[8], gy[8];
#pragma unroll
    for (int j = 0; j < 8; ++j) {
        const float t0 = row[0][j], t1 = row[0][j + 1], t2 = row[0][j + 2];
        const float m0 = row[1][j],                      m2 = row[1][j + 2];
        const float b0 = row[2][j], b1 = row[2][j + 1], b2 = row[2][j + 2];
        gx[j] = ((((t0 - t2) + 2.0f * m0) - 2.0f * m2) + b0) - b2;
        gy[j] = ((((t0 + 2.0f * t1) + t2) - b0) - 2.0f * b1) - b2;
    }

    // ---- stage C: mag + fold + octant + rcp x8 (trans ops pipelined) ----
    float mg[8], t_[8], ays[8];   // ays: folded ay (sign info for w select)
    bool  qs[8];
#pragma unroll
    for (int j = 0; j < 8; ++j) {
        mg[j] = sqrtf(gx[j] * gx[j] + gy[j] * gy[j]);
        const float ax = fabsf(gx[j]);
        const float ay = __uint_as_float(__float_as_uint(gy[j]) ^
                                         (__float_as_uint(gx[j]) & 0x80000000u));
        const float aay = fabsf(ay);
        const bool  q   = ax > aay;
        const float den = q ? ax : aay;
        const float num = q ? ay : ax;
        t_[j]  = num * __frcp_rn(den);
        ays[j] = ay;
        qs[j]  = q;
    }

    // ---- stage D: polynomial x8 ----
    float w_[8];
#pragma unroll
    for (int j = 0; j < 8; ++j) {
        const float u = t_[j] * t_[j];
        float p = fmaf(P4, u, P3);
        p = fmaf(p, u, P2);
        p = fmaf(p, u, P1);
        p = fmaf(p, u, P0);
        const float s = t_[j] * p;
        w_[j] = qs[j] ? (5.0f - s) : ((ays[j] > 0.0f) ? s : (10.0f - s));
    }

    // ---- stage E+F: flag, bin, gated scatter x8 ----
    float acc[NB];
#pragma unroll
    for (int b = 0; b < NB; ++b) acc[b] = 0.0f;

    int flags = 0;
#pragma unroll
    for (int j = 0; j < 8; ++j) {
        const float w = w_[j];
        const float dist = fabsf(w - rintf(w));
        const bool flagged = !(dist >= EPSW);   // NaN-safe (mag==0 -> flagged)
        flags |= flagged ? (1 << j) : 0;
        const int   bi  = (int)w;               // trunc==floor on (0,10)
        const float dep = flagged ? 0.0f : mg[j];
#pragma unroll
        for (int b = 0; b < NB; ++b) acc[b] += (bi == b) ? dep : 0.0f;
    }

    // ---- stage G: slow path (verbatim R12), once per strip, uses saved gx/gy ----
    if (flags) {
#pragma unroll
        for (int j = 0; j < 8; ++j) {
            if (flags & (1 << j)) {
                const float gxx = gx[j], gyy = gy[j];
                const float mag = mg[j];
                const float phs = atan2f(gxx, gyy);     // OCML -- pinned
                const float w10 = __fmul_rn(phs, C10);
                int bi = (int)floorf(w10);
                bi %= 10;
                if (bi < 0) bi += 10;
                float half = 0.0f;
                int   balt = 0;
                const float rk  = rintf(w10);
                const float eps = fmaxf(4.0f * fabsf(w10) * 1.1920929e-7f, 1.5e-6f);
                if (fabsf(w10 - rk) < eps && mag < 4.6f) {
                    const int k  = (int)rk;
                    int kb = k % 10;       if (kb < 0) kb += 10;
                    int ka = (k - 1) % 10; if (ka < 0) ka += 10;
                    balt = (bi == kb) ? ka : kb;
                    half = 0.5f * mag;
                }
                const float dep = mag - half;
#pragma unroll
                for (int b = 0; b < NB; ++b) acc[b] += (bi == b) ? dep : 0.0f;
                if (half > 0.0f) {
#pragma unroll
                    for (int b = 0; b < NB; ++b) acc[b] += (balt == b) ? half : 0.0f;
                }
            }
        }
    }

    // ---- stage H: reduce the 8 row-lanes of each cell, write ----
    float w1 = 0.0f, w2 = 0.0f;
#pragma unroll
    for (int b = 0; b < NB; ++b) {
        float v = acc[b];
        v += __shfl_xor(v, 1, 64);
        v += __shfl_xor(v, 2, 64);
        v += __shfl_xor(v, 4, 64);
        if (b < 8) { w1 = (r == b)     ? v : w1; }
        else       { w2 = (r == b - 8) ? v : w2; }
    }

    const float inv = 1.0f / 64.0f;
    const size_t obase = (((size_t)n * NB) * 64 + (size_t)ph) * 64 + (size_t)pw;
    out[obase + (size_t)r * 4096] = w1 * inv;
    if (r < 2) out[obase + (size_t)(8 + r) * 4096] = w2 * inv;
}

extern "C" void kernel_launch(void* const* d_in, const int* in_sizes, int n_in,
                              void* d_out, int out_size, void* d_ws, size_t ws_size,
                              hipStream_t stream) {
    const float* x = (const float*)d_in[0];
    float* out = (float*)d_out;
    hipLaunchKernelGGL(hog_kernel, dim3(4096), dim3(256), 0, stream, x, out);
}

// Round 20
// 27.165 us; speedup vs baseline: 1.0972x; 1.0972x over previous
//
#include <hip/hip_runtime.h>

// HOG layer: (32,1,512,512) f32 -> (32,10,64,64) f32
// CORRECTNESS-PINNED decisions (R12 pass, absmax 0.0371):
//   f32 seq conv (row-major sequential taps) -> bin = floor(fl32(atan2f*C10))
//   mod 10 with boundary-ambiguity 50/50 split (eps window, mag<4.6 gate)
//   -> 8x8 mean pool.
// Fast path (R17, bit-identical): octant-reduced Hastings deg-9 atan in w10
// units; |w - rint(w)| < 1.25e-4 -> flagged -> VERBATIM R12 slow path inline.
// R20 (data movement only): lane owns a 4x8 HALF-CELL (32 px). 3-row window
// slides down 6 rows held in statically-named register arrays (halo rows
// reused vertically: 1.87 loads/px vs 3.75). Cell reduce = ONE shfl_xor(1)
// + add per bin (partner lane = other half); h-lane writes 5 bin planes.
// Summation regrouping is commutative-exact; deposit values unchanged.

namespace {
constexpr int H = 512, W = 512, NB = 10;
}

__device__ __forceinline__ void load_row(const float* __restrict__ img,
                                         int ry, int x0, bool lok, bool rok,
                                         float (&R)[10]) {
    if (ry >= 0 && ry < H) {
        const float* p = img + (size_t)ry * W + x0;
        R[0] = lok ? p[-1] : 0.0f;
        const float4 a = *reinterpret_cast<const float4*>(p);      // 32B-aligned
        const float4 b = *reinterpret_cast<const float4*>(p + 4);
        R[1] = a.x; R[2] = a.y; R[3] = a.z; R[4] = a.w;
        R[5] = b.x; R[6] = b.y; R[7] = b.z; R[8] = b.w;
        R[9] = rok ? p[8] : 0.0f;
    } else {
#pragma unroll
        for (int i = 0; i < 10; ++i) R[i] = 0.0f;
    }
}

__global__ __launch_bounds__(256) void hog_kernel(const float* __restrict__ xin,
                                                  float* __restrict__ out) {
    const int tid  = threadIdx.x;
    const int wid  = (blockIdx.x << 2) + (tid >> 6);   // global wave id, 0..4095
    const int lane = tid & 63;

    const int c  = lane >> 1;          // cell within wave, 0..31
    const int h  = lane & 1;           // half: 0 = rows 0-3, 1 = rows 4-7

    const int cg  = (wid << 5) + c;    // global cell id
    const int n   = cg >> 12;          // image
    const int rem = cg & 4095;
    const int ph  = rem >> 6;          // pooled row 0..63
    const int pw  = rem & 63;          // pooled col 0..63

    const int x0 = pw * 8;
    const int yb = ph * 8 + h * 4;     // first owned row

    const float* img = xin + (size_t)n * H * W;
    const bool lok = (pw > 0), rok = (pw < 63);

    // pinned: C10 = fl32( fl32(1/pi32) * 10 )
    const float PI32 = 3.14159274101257324f;            // 0x40490fdb
    const float C10  = __fmul_rn(__fdiv_rn(1.0f, PI32), 10.0f);

    // Hastings (A&S 4.4.47) atan coeffs scaled by 10/pi (w10 units) -- pinned
    const float P0 =  3.1826723f, P1 = -1.0513758f, P2 = 0.5734066f,
                P3 = -0.2709868f, P4 =  0.0663202f;
    const float EPSW = 1.25e-4f;

    float acc[NB];
#pragma unroll
    for (int b = 0; b < NB; ++b) acc[b] = 0.0f;

    // per-row pipeline (R17 verbatim, inline slow path)
    auto process_row = [&](const float (&T)[10], const float (&M)[10],
                           const float (&B)[10]) {
#pragma unroll
        for (int j = 0; j < 8; ++j) {
            const float t0 = T[j], t1 = T[j + 1], t2 = T[j + 2];
            const float m0 = M[j],                 m2 = M[j + 2];
            const float b0 = B[j], b1 = B[j + 1], b2 = B[j + 2];

            // pinned: f32 conv, sequential row-major taps
            const float gx = ((((t0 - t2) + 2.0f * m0) - 2.0f * m2) + b0) - b2;
            const float gy = ((((t0 + 2.0f * t1) + t2) - b0) - 2.0f * b1) - b2;

            const float mag = sqrtf(gx * gx + gy * gy);

            // fold to [0,pi): ax=|gx|, ay = gy ^ sign(gx)  (gx==0 -> flagged)
            const float ax  = fabsf(gx);
            const float ay  = __uint_as_float(__float_as_uint(gy) ^
                                              (__float_as_uint(gx) & 0x80000000u));
            const float aay = fabsf(ay);

            const bool  q   = ax > aay;
            const float den = q ? ax : aay;
            const float num = q ? ay : ax;
            const float t   = num * __frcp_rn(den);
            const float u   = t * t;
            float p = fmaf(P4, u, P3);
            p = fmaf(p, u, P2);
            p = fmaf(p, u, P1);
            p = fmaf(p, u, P0);
            const float s = t * p;                      // atan in w10 units
            const float w = q ? (5.0f - s) : ((ay > 0.0f) ? s : (10.0f - s));

            const float dist = fabsf(w - rintf(w));
            const bool flagged = !(dist >= EPSW);       // NaN-safe

            int   bi;
            float half = 0.0f;
            int   balt = 0;
            if (!flagged) {
                bi = (int)w;                            // trunc==floor on (0,10)
            } else {
                // ---- R12 slow path, verbatim ----
                const float phs = atan2f(gx, gy);       // OCML -- pinned
                const float w10 = __fmul_rn(phs, C10);
                bi = (int)floorf(w10);
                bi %= 10;
                if (bi < 0) bi += 10;
                const float rk  = rintf(w10);
                const float eps = fmaxf(4.0f * fabsf(w10) * 1.1920929e-7f, 1.5e-6f);
                if (fabsf(w10 - rk) < eps && mag < 4.6f) {
                    const int k  = (int)rk;
                    int kb = k % 10;       if (kb < 0) kb += 10;
                    int ka = (k - 1) % 10; if (ka < 0) ka += 10;
                    balt = (bi == kb) ? ka : kb;
                    half = 0.5f * mag;
                }
            }

            const float dep = mag - half;
#pragma unroll
            for (int b = 0; b < NB; ++b) acc[b] += (bi == b) ? dep : 0.0f;
            if (half > 0.0f) {                          // rare: execz-skipped
#pragma unroll
                for (int b = 0; b < NB; ++b) acc[b] += (balt == b) ? half : 0.0f;
            }
        }
    };

    // 6-row sliding window in statically-named buffers (no rotation movs)
    float R0[10], R1[10], R2[10], R3[10], R4[10], R5[10];
    load_row(img, yb - 1, x0, lok, rok, R0);
    load_row(img, yb,     x0, lok, rok, R1);
    load_row(img, yb + 1, x0, lok, rok, R2);
    load_row(img, yb + 2, x0, lok, rok, R3);   // prefetch
    process_row(R0, R1, R2);
    load_row(img, yb + 3, x0, lok, rok, R4);   // prefetch
    process_row(R1, R2, R3);
    load_row(img, yb + 4, x0, lok, rok, R5);   // prefetch
    process_row(R2, R3, R4);
    process_row(R3, R4, R5);

    // cell reduce: partner lane (other half) via one xor-1 shuffle per bin
    float v0 = 0.0f, v1 = 0.0f, v2 = 0.0f, v3 = 0.0f, v4 = 0.0f;
#pragma unroll
    for (int b = 0; b < NB; ++b) {
        const float vb = acc[b] + __shfl_xor(acc[b], 1, 64);   // commutative-exact
        // this lane writes bins h*5+q; select statically over q, ternary over h
        const int q5 = b - (b >= 5 ? 5 : 0);       // b mod 5
        const bool mine = (b >= 5) == (h == 1);
        if (mine) {
            v0 = (q5 == 0) ? vb : v0;
            v1 = (q5 == 1) ? vb : v1;
            v2 = (q5 == 2) ? vb : v2;
            v3 = (q5 == 3) ? vb : v3;
            v4 = (q5 == 4) ? vb : v4;
        }
    }

    const float inv = 1.0f / 64.0f;
    // out[((n*10 + b)*64 + ph)*64 + pw], b = h*5 + q, b-plane stride 4096
    const size_t obase = (((size_t)n * NB) * 64 + (size_t)ph) * 64 + (size_t)pw
                       + (size_t)h * 5 * 4096;
    out[obase]               = v0 * inv;
    out[obase + 1 * 4096]    = v1 * inv;
    out[obase + 2 * 4096]    = v2 * inv;
    out[obase + 3 * 4096]    = v3 * inv;
    out[obase + 4 * 4096]    = v4 * inv;
}

extern "C" void kernel_launch(void* const* d_in, const int* in_sizes, int n_in,
                              void* d_out, int out_size, void* d_ws, size_t ws_size,
                              hipStream_t stream) {
    const float* x = (const float*)d_in[0];
    float* out = (float*)d_out;
    // 131072 cells / 32 per wave = 4096 waves -> 1024 blocks of 256 threads
    hipLaunchKernelGGL(hog_kernel, dim3(1024), dim3(256), 0, stream, x, out);
}

// Round 21
// 23.840 us; speedup vs baseline: 1.2503x; 1.1395x over previous
//
#include <hip/hip_runtime.h>

// HOG layer: (32,1,512,512) f32 -> (32,10,64,64) f32
// CORRECTNESS-PINNED decisions (R12 pass, absmax 0.0371):
//   f32 seq conv (row-major sequential taps) -> bin = floor(fl32(atan2f*C10))
//   mod 10 with boundary-ambiguity 50/50 split (eps window, mag<4.6 gate)
//   -> 8x8 mean pool.
// Fast path (R17): octant-reduced Hastings deg-9 atan in w10 units;
// |w - rint(w)| < 1.25e-4 -> flagged -> VERBATIM R12 slow path inline.
// R20 structure: lane owns a 4x8 half-cell, 6-row static window, xor-1 reduce.
// R21 change: raw transcendentals. sqrtf (IEEE, ~7-inst refine) ->
// __builtin_amdgcn_sqrtf (1 v_sqrt_f32; mag only scales deposits, 2% tol);
// __frcp_rn (correctly-rounded, multi-inst fixup) -> __builtin_amdgcn_rcpf
// (1 v_rcp_f32, 1 ulp = exactly what the R17 error budget assumed; EPSW
// margin 3.5x intact, split-window coverage unchanged).

namespace {
constexpr int H = 512, W = 512, NB = 10;
}

__device__ __forceinline__ void load_row(const float* __restrict__ img,
                                         int ry, int x0, bool lok, bool rok,
                                         float (&R)[10]) {
    if (ry >= 0 && ry < H) {
        const float* p = img + (size_t)ry * W + x0;
        R[0] = lok ? p[-1] : 0.0f;
        const float4 a = *reinterpret_cast<const float4*>(p);      // 32B-aligned
        const float4 b = *reinterpret_cast<const float4*>(p + 4);
        R[1] = a.x; R[2] = a.y; R[3] = a.z; R[4] = a.w;
        R[5] = b.x; R[6] = b.y; R[7] = b.z; R[8] = b.w;
        R[9] = rok ? p[8] : 0.0f;
    } else {
#pragma unroll
        for (int i = 0; i < 10; ++i) R[i] = 0.0f;
    }
}

__global__ __launch_bounds__(256) void hog_kernel(const float* __restrict__ xin,
                                                  float* __restrict__ out) {
    const int tid  = threadIdx.x;
    const int wid  = (blockIdx.x << 2) + (tid >> 6);   // global wave id, 0..4095
    const int lane = tid & 63;

    const int c  = lane >> 1;          // cell within wave, 0..31
    const int h  = lane & 1;           // half: 0 = rows 0-3, 1 = rows 4-7

    const int cg  = (wid << 5) + c;    // global cell id
    const int n   = cg >> 12;          // image
    const int rem = cg & 4095;
    const int ph  = rem >> 6;          // pooled row 0..63
    const int pw  = rem & 63;          // pooled col 0..63

    const int x0 = pw * 8;
    const int yb = ph * 8 + h * 4;     // first owned row

    const float* img = xin + (size_t)n * H * W;
    const bool lok = (pw > 0), rok = (pw < 63);

    // pinned: C10 = fl32( fl32(1/pi32) * 10 )
    const float PI32 = 3.14159274101257324f;            // 0x40490fdb
    const float C10  = __fmul_rn(__fdiv_rn(1.0f, PI32), 10.0f);

    // Hastings (A&S 4.4.47) atan coeffs scaled by 10/pi (w10 units) -- pinned
    const float P0 =  3.1826723f, P1 = -1.0513758f, P2 = 0.5734066f,
                P3 = -0.2709868f, P4 =  0.0663202f;
    const float EPSW = 1.25e-4f;

    float acc[NB];
#pragma unroll
    for (int b = 0; b < NB; ++b) acc[b] = 0.0f;

    // per-row pipeline (R17 verbatim decisions, raw transcendentals)
    auto process_row = [&](const float (&T)[10], const float (&M)[10],
                           const float (&B)[10]) {
#pragma unroll
        for (int j = 0; j < 8; ++j) {
            const float t0 = T[j], t1 = T[j + 1], t2 = T[j + 2];
            const float m0 = M[j],                 m2 = M[j + 2];
            const float b0 = B[j], b1 = B[j + 1], b2 = B[j + 2];

            // pinned: f32 conv, sequential row-major taps
            const float gx = ((((t0 - t2) + 2.0f * m0) - 2.0f * m2) + b0) - b2;
            const float gy = ((((t0 + 2.0f * t1) + t2) - b0) - 2.0f * b1) - b2;

            // raw v_sqrt_f32: mag only scales deposits (2% tolerance)
            const float mag = __builtin_amdgcn_sqrtf(gx * gx + gy * gy);

            // fold to [0,pi): ax=|gx|, ay = gy ^ sign(gx)  (gx==0 -> flagged)
            const float ax  = fabsf(gx);
            const float ay  = __uint_as_float(__float_as_uint(gy) ^
                                              (__float_as_uint(gx) & 0x80000000u));
            const float aay = fabsf(ay);

            const bool  q   = ax > aay;
            const float den = q ? ax : aay;
            const float num = q ? ay : ax;
            const float t   = num * __builtin_amdgcn_rcpf(den);   // raw v_rcp, 1 ulp
            const float u   = t * t;
            float p = fmaf(P4, u, P3);
            p = fmaf(p, u, P2);
            p = fmaf(p, u, P1);
            p = fmaf(p, u, P0);
            const float s = t * p;                      // atan in w10 units
            const float w = q ? (5.0f - s) : ((ay > 0.0f) ? s : (10.0f - s));

            const float dist = fabsf(w - rintf(w));
            const bool flagged = !(dist >= EPSW);       // NaN-safe

            int   bi;
            float half = 0.0f;
            int   balt = 0;
            if (!flagged) {
                bi = (int)w;                            // trunc==floor on (0,10)
            } else {
                // ---- R12 slow path, verbatim ----
                const float phs = atan2f(gx, gy);       // OCML -- pinned
                const float w10 = __fmul_rn(phs, C10);
                bi = (int)floorf(w10);
                bi %= 10;
                if (bi < 0) bi += 10;
                const float rk  = rintf(w10);
                const float eps = fmaxf(4.0f * fabsf(w10) * 1.1920929e-7f, 1.5e-6f);
                if (fabsf(w10 - rk) < eps && mag < 4.6f) {
                    const int k  = (int)rk;
                    int kb = k % 10;       if (kb < 0) kb += 10;
                    int ka = (k - 1) % 10; if (ka < 0) ka += 10;
                    balt = (bi == kb) ? ka : kb;
                    half = 0.5f * mag;
                }
            }

            const float dep = mag - half;
#pragma unroll
            for (int b = 0; b < NB; ++b) acc[b] += (bi == b) ? dep : 0.0f;
            if (half > 0.0f) {                          // rare: execz-skipped
#pragma unroll
                for (int b = 0; b < NB; ++b) acc[b] += (balt == b) ? half : 0.0f;
            }
        }
    };

    // 6-row sliding window in statically-named buffers (no rotation movs)
    float R0[10], R1[10], R2[10], R3[10], R4[10], R5[10];
    load_row(img, yb - 1, x0, lok, rok, R0);
    load_row(img, yb,     x0, lok, rok, R1);
    load_row(img, yb + 1, x0, lok, rok, R2);
    load_row(img, yb + 2, x0, lok, rok, R3);   // prefetch
    process_row(R0, R1, R2);
    load_row(img, yb + 3, x0, lok, rok, R4);   // prefetch
    process_row(R1, R2, R3);
    load_row(img, yb + 4, x0, lok, rok, R5);   // prefetch
    process_row(R2, R3, R4);
    process_row(R3, R4, R5);

    // cell reduce: partner lane (other half) via one xor-1 shuffle per bin
    float v0 = 0.0f, v1 = 0.0f, v2 = 0.0f, v3 = 0.0f, v4 = 0.0f;
#pragma unroll
    for (int b = 0; b < NB; ++b) {
        const float vb = acc[b] + __shfl_xor(acc[b], 1, 64);   // commutative-exact
        const int q5 = b - (b >= 5 ? 5 : 0);       // b mod 5
        const bool mine = (b >= 5) == (h == 1);
        if (mine) {
            v0 = (q5 == 0) ? vb : v0;
            v1 = (q5 == 1) ? vb : v1;
            v2 = (q5 == 2) ? vb : v2;
            v3 = (q5 == 3) ? vb : v3;
            v4 = (q5 == 4) ? vb : v4;
        }
    }

    const float inv = 1.0f / 64.0f;
    // out[((n*10 + b)*64 + ph)*64 + pw], b = h*5 + q, b-plane stride 4096
    const size_t obase = (((size_t)n * NB) * 64 + (size_t)ph) * 64 + (size_t)pw
                       + (size_t)h * 5 * 4096;
    out[obase]               = v0 * inv;
    out[obase + 1 * 4096]    = v1 * inv;
    out[obase + 2 * 4096]    = v2 * inv;
    out[obase + 3 * 4096]    = v3 * inv;
    out[obase + 4 * 4096]    = v4 * inv;
}

extern "C" void kernel_launch(void* const* d_in, const int* in_sizes, int n_in,
                              void* d_out, int out_size, void* d_ws, size_t ws_size,
                              hipStream_t stream) {
    const float* x = (const float*)d_in[0];
    float* out = (float*)d_out;
    // 131072 cells / 32 per wave = 4096 waves -> 1024 blocks of 256 threads
    hipLaunchKernelGGL(hog_kernel, dim3(1024), dim3(256), 0, stream, x, out);
}

// Round 22
// 21.063 us; speedup vs baseline: 1.4151x; 1.1318x over previous
//
#include <hip/hip_runtime.h>

// HOG layer: (32,1,512,512) f32 -> (32,10,64,64) f32
// CORRECTNESS-PINNED decisions (R12 pass, absmax 0.0371):
//   f32 seq conv (row-major sequential taps) -> bin = floor(fl32(atan2f*C10))
//   mod 10 with boundary-ambiguity 50/50 split (eps window, mag<4.6 gate)
//   -> 8x8 mean pool.
// Fast path (R17): octant-reduced Hastings deg-9 atan in w10 units;
// |w - rint(w)| < 1.25e-4 -> flagged -> VERBATIM R12 slow path inline.
// R20 structure: lane owns 4x8 half-cell, 6-row static window, xor-1 reduce.
// R21: raw v_sqrt_f32 / v_rcp_f32 (error budget unchanged).
// R22: (a) bin-pair packed accumulator acc2[5] f32x2 (.x=bin q, .y=bin q+5),
// deposit via 5x v_pk_fma with 1.0/0.0 gate (bit-exact: +0 adds, acc>=0);
// (b) balt/half deposit folded INSIDE the flagged branch (half>0 => flagged),
// removing one exec-mask sequence per pixel. Reduce does the same two adds
// in the same order per bin -> bit-identical output.

namespace {
constexpr int H = 512, W = 512, NB = 10;
}

typedef __attribute__((ext_vector_type(2))) float f32x2;

__device__ __forceinline__ f32x2 vfma2(f32x2 a, f32x2 b, f32x2 c) {
#if __has_builtin(__builtin_elementwise_fma)
    return __builtin_elementwise_fma(a, b, c);
#else
    f32x2 r; r.x = fmaf(a.x, b.x, c.x); r.y = fmaf(a.y, b.y, c.y); return r;
#endif
}

__device__ __forceinline__ void load_row(const float* __restrict__ img,
                                         int ry, int x0, bool lok, bool rok,
                                         float (&R)[10]) {
    if (ry >= 0 && ry < H) {
        const float* p = img + (size_t)ry * W + x0;
        R[0] = lok ? p[-1] : 0.0f;
        const float4 a = *reinterpret_cast<const float4*>(p);      // 32B-aligned
        const float4 b = *reinterpret_cast<const float4*>(p + 4);
        R[1] = a.x; R[2] = a.y; R[3] = a.z; R[4] = a.w;
        R[5] = b.x; R[6] = b.y; R[7] = b.z; R[8] = b.w;
        R[9] = rok ? p[8] : 0.0f;
    } else {
#pragma unroll
        for (int i = 0; i < 10; ++i) R[i] = 0.0f;
    }
}

__global__ __launch_bounds__(256) void hog_kernel(const float* __restrict__ xin,
                                                  float* __restrict__ out) {
    const int tid  = threadIdx.x;
    const int wid  = (blockIdx.x << 2) + (tid >> 6);   // global wave id, 0..4095
    const int lane = tid & 63;

    const int c  = lane >> 1;          // cell within wave, 0..31
    const int h  = lane & 1;           // half: 0 = rows 0-3, 1 = rows 4-7

    const int cg  = (wid << 5) + c;    // global cell id
    const int n   = cg >> 12;          // image
    const int rem = cg & 4095;
    const int ph  = rem >> 6;          // pooled row 0..63
    const int pw  = rem & 63;          // pooled col 0..63

    const int x0 = pw * 8;
    const int yb = ph * 8 + h * 4;     // first owned row

    const float* img = xin + (size_t)n * H * W;
    const bool lok = (pw > 0), rok = (pw < 63);

    // pinned: C10 = fl32( fl32(1/pi32) * 10 )
    const float PI32 = 3.14159274101257324f;            // 0x40490fdb
    const float C10  = __fmul_rn(__fdiv_rn(1.0f, PI32), 10.0f);

    // Hastings (A&S 4.4.47) atan coeffs scaled by 10/pi (w10 units) -- pinned
    const float P0 =  3.1826723f, P1 = -1.0513758f, P2 = 0.5734066f,
                P3 = -0.2709868f, P4 =  0.0663202f;
    const float EPSW = 1.25e-4f;

    f32x2 acc2[5];                     // .x = bin p, .y = bin p+5
#pragma unroll
    for (int p = 0; p < 5; ++p) acc2[p] = (f32x2){0.0f, 0.0f};

    // packed single-bin deposit: value v into bin b (0..9)
    auto deposit = [&](int b, float v) {
        const bool  hi = b >= 5;
        const int   q5 = hi ? (b - 5) : b;
        const f32x2 P  = hi ? (f32x2){0.0f, v} : (f32x2){v, 0.0f};
#pragma unroll
        for (int p = 0; p < 5; ++p) {
            const float g = (q5 == p) ? 1.0f : 0.0f;
            acc2[p] = vfma2(P, (f32x2){g, g}, acc2[p]);
        }
    };

    // per-row pipeline (R17 decisions verbatim, raw transcendentals)
    auto process_row = [&](const float (&T)[10], const float (&M)[10],
                           const float (&B)[10]) {
#pragma unroll
        for (int j = 0; j < 8; ++j) {
            const float t0 = T[j], t1 = T[j + 1], t2 = T[j + 2];
            const float m0 = M[j],                 m2 = M[j + 2];
            const float b0 = B[j], b1 = B[j + 1], b2 = B[j + 2];

            // pinned: f32 conv, sequential row-major taps
            const float gx = ((((t0 - t2) + 2.0f * m0) - 2.0f * m2) + b0) - b2;
            const float gy = ((((t0 + 2.0f * t1) + t2) - b0) - 2.0f * b1) - b2;

            const float mag = __builtin_amdgcn_sqrtf(gx * gx + gy * gy);

            // fold to [0,pi): ax=|gx|, ay = gy ^ sign(gx)  (gx==0 -> flagged)
            const float ax  = fabsf(gx);
            const float ay  = __uint_as_float(__float_as_uint(gy) ^
                                              (__float_as_uint(gx) & 0x80000000u));
            const float aay = fabsf(ay);

            const bool  q   = ax > aay;
            const float den = q ? ax : aay;
            const float num = q ? ay : ax;
            const float t   = num * __builtin_amdgcn_rcpf(den);   // 1 ulp
            const float u   = t * t;
            float p = fmaf(P4, u, P3);
            p = fmaf(p, u, P2);
            p = fmaf(p, u, P1);
            p = fmaf(p, u, P0);
            const float s = t * p;                      // atan in w10 units
            const float w = q ? (5.0f - s) : ((ay > 0.0f) ? s : (10.0f - s));

            const float dist = fabsf(w - rintf(w));
            const bool flagged = !(dist >= EPSW);       // NaN-safe

            int   bi;
            float dep;
            if (!flagged) {
                bi  = (int)w;                           // trunc==floor on (0,10)
                dep = mag;
            } else {
                // ---- R12 slow path, verbatim (rare: execz-skipped) ----
                const float phs = atan2f(gx, gy);       // OCML -- pinned
                const float w10 = __fmul_rn(phs, C10);
                bi = (int)floorf(w10);
                bi %= 10;
                if (bi < 0) bi += 10;
                float half = 0.0f;
                const float rk  = rintf(w10);
                const float eps = fmaxf(4.0f * fabsf(w10) * 1.1920929e-7f, 1.5e-6f);
                if (fabsf(w10 - rk) < eps && mag < 4.6f) {
                    const int k  = (int)rk;
                    int kb = k % 10;       if (kb < 0) kb += 10;
                    int ka = (k - 1) % 10; if (ka < 0) ka += 10;
                    const int balt = (bi == kb) ? ka : kb;
                    half = 0.5f * mag;
                    deposit(balt, half);                // balt != bi: order-safe
                }
                dep = mag - half;
            }

            deposit(bi, dep);
        }
    };

    // 6-row sliding window in statically-named buffers (no rotation movs)
    float R0[10], R1[10], R2[10], R3[10], R4[10], R5[10];
    load_row(img, yb - 1, x0, lok, rok, R0);
    load_row(img, yb,     x0, lok, rok, R1);
    load_row(img, yb + 1, x0, lok, rok, R2);
    load_row(img, yb + 2, x0, lok, rok, R3);   // prefetch
    process_row(R0, R1, R2);
    load_row(img, yb + 3, x0, lok, rok, R4);   // prefetch
    process_row(R1, R2, R3);
    load_row(img, yb + 4, x0, lok, rok, R5);   // prefetch
    process_row(R2, R3, R4);
    process_row(R3, R4, R5);

    // cell reduce: partner lane (other half) via one xor-1 shuffle per pair
    float v0 = 0.0f, v1 = 0.0f, v2 = 0.0f, v3 = 0.0f, v4 = 0.0f;
#pragma unroll
    for (int p = 0; p < 5; ++p) {
        const float sx = acc2[p].x + __shfl_xor(acc2[p].x, 1, 64);  // bins 0-4
        const float sy = acc2[p].y + __shfl_xor(acc2[p].y, 1, 64);  // bins 5-9
        const float vq = h ? sy : sx;        // this lane's owned bin h*5+p
        v0 = (p == 0) ? vq : v0;
        v1 = (p == 1) ? vq : v1;
        v2 = (p == 2) ? vq : v2;
        v3 = (p == 3) ? vq : v3;
        v4 = (p == 4) ? vq : v4;
    }

    const float inv = 1.0f / 64.0f;
    // out[((n*10 + b)*64 + ph)*64 + pw], b = h*5 + p, b-plane stride 4096
    const size_t obase = (((size_t)n * NB) * 64 + (size_t)ph) * 64 + (size_t)pw
                       + (size_t)h * 5 * 4096;
    out[obase]            = v0 * inv;
    out[obase + 1 * 4096] = v1 * inv;
    out[obase + 2 * 4096] = v2 * inv;
    out[obase + 3 * 4096] = v3 * inv;
    out[obase + 4 * 4096] = v4 * inv;
}

extern "C" void kernel_launch(void* const* d_in, const int* in_sizes, int n_in,
                              void* d_out, int out_size, void* d_ws, size_t ws_size,
                              hipStream_t stream) {
    const float* x = (const float*)d_in[0];
    float* out = (float*)d_out;
    // 131072 cells / 32 per wave = 4096 waves -> 1024 blocks of 256 threads
    hipLaunchKernelGGL(hog_kernel, dim3(1024), dim3(256), 0, stream, x, out);
}